// Round 1
// baseline (321.140 us; speedup 1.0000x reference)
//
#include <hip/hip_runtime.h>

// DiffTreeInterpreter: gather formulation.
// out[b,r,:] = op0*carA[b,2r] (r<2048)
//            + op1*cdrA[b,2r+1] (1<=r<2048)
//            + op2*(r even ? c1[b,r/2] : c2[b,(r-1)/2])
//            + (r==1 ? op2*root_filler[b] : 0)
// where {car,cdr,c1,c2}A[b,role] = sum_{tokens n: batch=b, role=role} w_k[n]*mem[n,:]
// pad-masking in the reference is a numeric no-op (padded rows are all-zero).

namespace {
constexpr int kB = 32;
constexpr int kL = 128;
constexpr int kF = 128;
constexpr int kR = 4096;
constexpr int kN = 262144;
constexpr int kNB = kB * kR;      // 131072 buckets
constexpr int kCap = 32;          // bucket capacity (Poisson mean 2 -> overflow ~1e-27)
constexpr int kOvfMax = 4096;

// workspace layout (bytes)
constexpr size_t kOffCounts = 0;                           // kNB * 4       = 524288
constexpr size_t kOffOvfCnt = (size_t)kNB * 4;             // 4
constexpr size_t kOffOvf    = kOffOvfCnt + 16;             // kOvfMax * 4
constexpr size_t kOffTokW   = 544768;                      // kN * 16       = 4194304
constexpr size_t kOffBuck   = kOffTokW + (size_t)kN * 16;  // kNB * kCap * 4 = 16777216
// total: 21,516,288 bytes (~20.5 MB)
}  // namespace

__global__ __launch_bounds__(256) void build_kernel(
    const float4* __restrict__ aw, const int* __restrict__ bidx,
    const int* __restrict__ sidx, const int* __restrict__ ridx,
    int* __restrict__ counts, int* __restrict__ ovf_cnt,
    int* __restrict__ ovf, float4* __restrict__ tokw,
    int* __restrict__ buckets) {
  int n = blockIdx.x * 256 + threadIdx.x;
  if (n >= kN) return;
  int b = bidx[n];
  int s = sidx[n];
  int rr = ridx[n];
  tokw[n] = aw[b * kL + s];  // cache per-token (w0,w1,w2,w3)
  int key = (b << 12) | rr;
  int pos = atomicAdd(&counts[key], 1);
  if (pos < kCap) {
    buckets[(size_t)key * kCap + pos] = n;
  } else {
    int o = atomicAdd(ovf_cnt, 1);
    if (o < kOvfMax) ovf[o] = n;
  }
}

__global__ __launch_bounds__(256) void gather_kernel(
    const float2* __restrict__ mem2, const float4* __restrict__ tokw,
    const float2* __restrict__ root2, const float* __restrict__ opd,
    const int* __restrict__ counts, const int* __restrict__ buckets,
    float2* __restrict__ out2) {
  const int row = blockIdx.x * 4 + (threadIdx.x >> 6);  // one wave per output row
  const int t = threadIdx.x & 63;                       // lane: features 2t, 2t+1
  const int b = row >> 12;
  const int r = row & (kR - 1);
  const float op0 = opd[3 * b + 0];
  const float op1 = opd[3 * b + 1];
  const float op2 = opd[3 * b + 2];
  float ax = 0.f, ay = 0.f;
  const int tcl = (t < kCap) ? t : (kCap - 1);  // lanes 0..31 preload bucket slots

  // ---- cons: bucket role r>>1, weight op2 * (r even ? w2 : w3). Always valid.
  {
    const int key = (b << 12) | (r >> 1);
    int cnt = min(counts[key], kCap);
    cnt = __builtin_amdgcn_readfirstlane(cnt);
    const int* bk = buckets + (size_t)key * kCap;
    int myidx = bk[tcl];
    const bool odd = (r & 1) != 0;
    for (int i = 0; i < cnt; ++i) {
      int n = __builtin_amdgcn_readfirstlane(__shfl(myidx, i));
      float4 w = tokw[n];
      float sc = op2 * (odd ? w.w : w.z);
      float2 m = mem2[(size_t)n * (kF / 2) + t];
      ax += sc * m.x;
      ay += sc * m.y;
    }
  }
  if (r < kR / 2) {
    // ---- car: bucket role 2r, weight op0*w0.
    {
      const int key = (b << 12) | (r << 1);
      int cnt = min(counts[key], kCap);
      cnt = __builtin_amdgcn_readfirstlane(cnt);
      const int* bk = buckets + (size_t)key * kCap;
      int myidx = bk[tcl];
      for (int i = 0; i < cnt; ++i) {
        int n = __builtin_amdgcn_readfirstlane(__shfl(myidx, i));
        float4 w = tokw[n];
        float sc = op0 * w.x;
        float2 m = mem2[(size_t)n * (kF / 2) + t];
        ax += sc * m.x;
        ay += sc * m.y;
      }
    }
    // ---- cdr: bucket role 2r+1, weight op1*w1, only for r>=1.
    if (r >= 1) {
      const int key = (b << 12) | ((r << 1) | 1);
      int cnt = min(counts[key], kCap);
      cnt = __builtin_amdgcn_readfirstlane(cnt);
      const int* bk = buckets + (size_t)key * kCap;
      int myidx = bk[tcl];
      for (int i = 0; i < cnt; ++i) {
        int n = __builtin_amdgcn_readfirstlane(__shfl(myidx, i));
        float4 w = tokw[n];
        float sc = op1 * w.y;
        float2 m = mem2[(size_t)n * (kF / 2) + t];
        ax += sc * m.x;
        ay += sc * m.y;
      }
    }
  }
  if (r == 1) {
    float2 rf = root2[b * (kF / 2) + t];
    ax += op2 * rf.x;
    ay += op2 * rf.y;
  }
  float2 o;
  o.x = ax;
  o.y = ay;
  out2[(size_t)row * (kF / 2) + t] = o;
}

// Fallback for bucket overflow (expected count 0): direct atomic scatter.
// Must run AFTER gather_kernel (gather writes out with '=').
__global__ __launch_bounds__(128) void ovf_kernel(
    const float* __restrict__ mem, const float4* __restrict__ tokw,
    const float* __restrict__ opd, const int* __restrict__ bidx,
    const int* __restrict__ ridx, const int* __restrict__ ovf_cnt,
    const int* __restrict__ ovf, float* __restrict__ out) {
  int m = *ovf_cnt;
  if (m > kOvfMax) m = kOvfMax;
  const int t = threadIdx.x;  // feature 0..127
  for (int i = blockIdx.x; i < m; i += gridDim.x) {
    int n = ovf[i];
    int b = bidx[n];
    int rr = ridx[n];
    float4 w = tokw[n];
    float op0 = opd[3 * b + 0];
    float op1 = opd[3 * b + 1];
    float op2 = opd[3 * b + 2];
    float mv = mem[(size_t)n * kF + t];
    size_t base = ((size_t)b * kR) * kF;
    if ((rr & 1) == 0)
      atomicAdd(&out[base + (size_t)(rr >> 1) * kF + t], op0 * w.x * mv);
    if ((rr & 1) && rr >= 3)
      atomicAdd(&out[base + (size_t)((rr - 1) >> 1) * kF + t], op1 * w.y * mv);
    if (rr < kR / 2) {
      atomicAdd(&out[base + (size_t)(2 * rr) * kF + t], op2 * w.z * mv);
      atomicAdd(&out[base + (size_t)(2 * rr + 1) * kF + t], op2 * w.w * mv);
    }
  }
}

extern "C" void kernel_launch(void* const* d_in, const int* in_sizes, int n_in,
                              void* d_out, int out_size, void* d_ws, size_t ws_size,
                              hipStream_t stream) {
  const float* mem   = (const float*)d_in[0];   // (N, F)
  const float* aw    = (const float*)d_in[1];   // (B, L, 4)
  const float* rootf = (const float*)d_in[2];   // (B, F)
  const float* opd   = (const float*)d_in[3];   // (B, 3)
  const int* bidx    = (const int*)d_in[4];     // (N,)
  const int* sidx    = (const int*)d_in[5];     // (N,)
  const int* ridx    = (const int*)d_in[6];     // (N,)

  char* ws = (char*)d_ws;
  int* counts    = (int*)(ws + kOffCounts);
  int* ovf_cnt   = (int*)(ws + kOffOvfCnt);
  int* ovf       = (int*)(ws + kOffOvf);
  float4* tokw   = (float4*)(ws + kOffTokW);
  int* buckets   = (int*)(ws + kOffBuck);

  // zero counts + overflow counter (ws is poisoned 0xAA before every call)
  hipMemsetAsync(ws, 0, kOffOvfCnt + 4, stream);

  build_kernel<<<kN / 256, 256, 0, stream>>>(
      (const float4*)aw, bidx, sidx, ridx, counts, ovf_cnt, ovf, tokw, buckets);

  gather_kernel<<<kNB / 4, 256, 0, stream>>>(
      (const float2*)mem, tokw, (const float2*)rootf, opd, counts, buckets,
      (float2*)d_out);

  ovf_kernel<<<64, 128, 0, stream>>>(
      mem, tokw, opd, bidx, ridx, ovf_cnt, ovf, (float*)d_out);
}

// Round 2
// 312.618 us; speedup vs baseline: 1.0273x; 1.0273x over previous
//
#include <hip/hip_runtime.h>

// DiffTreeInterpreter: gather formulation, batched-predicated-chunk edition.
// out[b,r,:] = carA[b,2r] (r<2048)            [weight op0*w0 folded into tokw.x]
//            + cdrA[b,2r+1] (1<=r<2048)       [op1*w1 -> tokw.y]
//            + (r even ? c1[b,r/2] : c2[b,(r-1)/2])  [op2*w2 -> tokw.z, op2*w3 -> tokw.w]
//            + (r==1 ? op2*root_filler[b] : 0)
// pad-masking in the reference is a numeric no-op (padded rows are all-zero).

namespace {
constexpr int kB = 32;
constexpr int kL = 128;
constexpr int kF = 128;
constexpr int kR = 4096;
constexpr int kN = 262144;
constexpr int kNB = kB * kR;      // 131072 buckets
constexpr int kCap = 32;          // bucket capacity (Poisson mean 2 -> overflow ~1e-27)
constexpr int kOvfMax = 4096;

// workspace layout (bytes)
constexpr size_t kOffCounts = 0;                           // kNB * 4       = 524288
constexpr size_t kOffOvfCnt = (size_t)kNB * 4;             // 4
constexpr size_t kOffOvf    = kOffOvfCnt + 16;             // kOvfMax * 4
constexpr size_t kOffTokW   = 544768;                      // kN * 16       = 4194304
constexpr size_t kOffBuck   = kOffTokW + (size_t)kN * 16;  // kNB * kCap * 4 = 16777216
// total: 21,516,288 bytes (~20.5 MB)
}  // namespace

__global__ __launch_bounds__(256) void build_kernel(
    const float4* __restrict__ aw, const float* __restrict__ opd,
    const int* __restrict__ bidx, const int* __restrict__ sidx,
    const int* __restrict__ ridx,
    int* __restrict__ counts, int* __restrict__ ovf_cnt,
    int* __restrict__ ovf, float4* __restrict__ tokw,
    int* __restrict__ buckets) {
  int n = blockIdx.x * 256 + threadIdx.x;
  if (n >= kN) return;
  int b = bidx[n];
  int s = sidx[n];
  int rr = ridx[n];
  float4 w = aw[b * kL + s];
  float op0 = opd[3 * b + 0];
  float op1 = opd[3 * b + 1];
  float op2 = opd[3 * b + 2];
  // premultiply op_dist into per-token weights
  float4 pw;
  pw.x = w.x * op0;
  pw.y = w.y * op1;
  pw.z = w.z * op2;
  pw.w = w.w * op2;
  tokw[n] = pw;
  int key = (b << 12) | rr;
  int pos = atomicAdd(&counts[key], 1);
  if (pos < kCap) {
    buckets[(size_t)key * kCap + pos] = n;
  } else {
    int o = atomicAdd(ovf_cnt, 1);
    if (o < kOvfMax) ovf[o] = n;
  }
}

// CH: 0 -> w.x (car), 1 -> w.y (cdr), 2 -> odd ? w.w : w.z (cons)
template <int CH>
__device__ __forceinline__ float pick_scale(float4 w, bool odd) {
  if (CH == 0) return w.x;
  if (CH == 1) return w.y;
  return odd ? w.w : w.z;
}

// Process predicated chunk of 4 bucket slots [i0, i0+4) (slots held across
// lanes of idxvec starting at laneoff). Invalid slots clamp n->0, scale->0.
template <int CH>
__device__ __forceinline__ void proc4(int i0, int cnt, int idxvec, int laneoff,
                                      bool odd,
                                      const float4* __restrict__ tokw,
                                      const float2* __restrict__ mem2, int t,
                                      float& ax, float& ay) {
  int n0 = __shfl(idxvec, laneoff + i0 + 0);
  int n1 = __shfl(idxvec, laneoff + i0 + 1);
  int n2 = __shfl(idxvec, laneoff + i0 + 2);
  int n3 = __shfl(idxvec, laneoff + i0 + 3);
  const bool v0 = (i0 + 0) < cnt, v1 = (i0 + 1) < cnt;
  const bool v2 = (i0 + 2) < cnt, v3 = (i0 + 3) < cnt;
  n0 = v0 ? n0 : 0;  // slots >= cnt hold 0xAA poison -> must clamp
  n1 = v1 ? n1 : 0;
  n2 = v2 ? n2 : 0;
  n3 = v3 ? n3 : 0;
  // 8 independent loads, one latency round
  float4 w0 = tokw[n0], w1 = tokw[n1], w2 = tokw[n2], w3 = tokw[n3];
  float2 m0 = mem2[(size_t)n0 * (kF / 2) + t];
  float2 m1 = mem2[(size_t)n1 * (kF / 2) + t];
  float2 m2 = mem2[(size_t)n2 * (kF / 2) + t];
  float2 m3 = mem2[(size_t)n3 * (kF / 2) + t];
  float s0 = v0 ? pick_scale<CH>(w0, odd) : 0.f;
  float s1 = v1 ? pick_scale<CH>(w1, odd) : 0.f;
  float s2 = v2 ? pick_scale<CH>(w2, odd) : 0.f;
  float s3 = v3 ? pick_scale<CH>(w3, odd) : 0.f;
  ax += s0 * m0.x; ay += s0 * m0.y;
  ax += s1 * m1.x; ay += s1 * m1.y;
  ax += s2 * m2.x; ay += s2 * m2.y;
  ax += s3 * m3.x; ay += s3 * m3.y;
}

__global__ __launch_bounds__(256) void gather_kernel(
    const float2* __restrict__ mem2, const float4* __restrict__ tokw,
    const float2* __restrict__ root2, const float* __restrict__ opd,
    const int* __restrict__ counts, const int* __restrict__ buckets,
    float2* __restrict__ out2) {
  const int row = blockIdx.x * 4 + (threadIdx.x >> 6);  // one wave per output row
  const int t = threadIdx.x & 63;                       // lane: features 2t, 2t+1
  const int ts = t & 31;
  const int b = row >> 12;
  const int r = row & (kR - 1);
  const bool odd = (r & 1) != 0;
  const bool lo = r < (kR / 2);

  const int keyC = (b << 12) | (r >> 1);               // cons bucket (always valid)
  const int keyA = (b << 12) | ((r << 1) & (kR - 1));  // car bucket (valid iff lo); even
  // cdr bucket = keyA | 1 (adjacent)

  // ---- issue ALL independent loads up front (1 latency round) ----
  int cntC_raw = counts[keyC];
  int2 cntAD_raw = *(const int2*)(counts + keyA);  // keyA even -> 8B aligned
  int idxC = buckets[(size_t)keyC * kCap + ts];            // slots 0..31 (x2)
  int idxAD = buckets[(size_t)keyA * kCap + t];            // lanes 0-31: car, 32-63: cdr

  const int cntC = min(cntC_raw, kCap);
  const int cntA = lo ? min(cntAD_raw.x, kCap) : 0;
  const int cntD = (lo && r >= 1) ? min(cntAD_raw.y, kCap) : 0;

  float ax = 0.f, ay = 0.f;

  // ---- first chunks: straight-line so all loads batch (1 more round) ----
  proc4<2>(0, cntC, idxC, 0, odd, tokw, mem2, t, ax, ay);
  if (lo) {
    proc4<0>(0, cntA, idxAD, 0, odd, tokw, mem2, t, ax, ay);
    proc4<1>(0, cntD, idxAD, 32, odd, tokw, mem2, t, ax, ay);
  }

  // ---- rare tails (P(count>4) ~ 5% per bucket) ----
  for (int i = 4; i < cntC; i += 4)
    proc4<2>(i, cntC, idxC, 0, odd, tokw, mem2, t, ax, ay);
  for (int i = 4; i < cntA; i += 4)
    proc4<0>(i, cntA, idxAD, 0, odd, tokw, mem2, t, ax, ay);
  for (int i = 4; i < cntD; i += 4)
    proc4<1>(i, cntD, idxAD, 32, odd, tokw, mem2, t, ax, ay);

  if (r == 1) {
    float2 rf = root2[b * (kF / 2) + t];
    float op2 = opd[3 * b + 2];
    ax += op2 * rf.x;
    ay += op2 * rf.y;
  }
  float2 o;
  o.x = ax;
  o.y = ay;
  out2[(size_t)row * (kF / 2) + t] = o;
}

// Fallback for bucket overflow (expected count 0): direct atomic scatter.
// tokw already has op_dist folded in. Must run AFTER gather_kernel.
__global__ __launch_bounds__(128) void ovf_kernel(
    const float* __restrict__ mem, const float4* __restrict__ tokw,
    const int* __restrict__ bidx, const int* __restrict__ ridx,
    const int* __restrict__ ovf_cnt, const int* __restrict__ ovf,
    float* __restrict__ out) {
  int m = *ovf_cnt;
  if (m > kOvfMax) m = kOvfMax;
  const int t = threadIdx.x;  // feature 0..127
  for (int i = blockIdx.x; i < m; i += gridDim.x) {
    int n = ovf[i];
    int b = bidx[n];
    int rr = ridx[n];
    float4 w = tokw[n];
    float mv = mem[(size_t)n * kF + t];
    size_t base = ((size_t)b * kR) * kF;
    if ((rr & 1) == 0)
      atomicAdd(&out[base + (size_t)(rr >> 1) * kF + t], w.x * mv);
    if ((rr & 1) && rr >= 3)
      atomicAdd(&out[base + (size_t)((rr - 1) >> 1) * kF + t], w.y * mv);
    if (rr < kR / 2) {
      atomicAdd(&out[base + (size_t)(2 * rr) * kF + t], w.z * mv);
      atomicAdd(&out[base + (size_t)(2 * rr + 1) * kF + t], w.w * mv);
    }
  }
}

extern "C" void kernel_launch(void* const* d_in, const int* in_sizes, int n_in,
                              void* d_out, int out_size, void* d_ws, size_t ws_size,
                              hipStream_t stream) {
  const float* mem   = (const float*)d_in[0];   // (N, F)
  const float* aw    = (const float*)d_in[1];   // (B, L, 4)
  const float* rootf = (const float*)d_in[2];   // (B, F)
  const float* opd   = (const float*)d_in[3];   // (B, 3)
  const int* bidx    = (const int*)d_in[4];     // (N,)
  const int* sidx    = (const int*)d_in[5];     // (N,)
  const int* ridx    = (const int*)d_in[6];     // (N,)

  char* ws = (char*)d_ws;
  int* counts    = (int*)(ws + kOffCounts);
  int* ovf_cnt   = (int*)(ws + kOffOvfCnt);
  int* ovf       = (int*)(ws + kOffOvf);
  float4* tokw   = (float4*)(ws + kOffTokW);
  int* buckets   = (int*)(ws + kOffBuck);

  // zero counts + overflow counter (ws is poisoned 0xAA before every call)
  hipMemsetAsync(ws, 0, kOffOvfCnt + 4, stream);

  build_kernel<<<kN / 256, 256, 0, stream>>>(
      (const float4*)aw, opd, bidx, sidx, ridx, counts, ovf_cnt, ovf, tokw,
      buckets);

  gather_kernel<<<kNB / 4, 256, 0, stream>>>(
      (const float2*)mem, tokw, (const float2*)rootf, opd, counts, buckets,
      (float2*)d_out);

  ovf_kernel<<<64, 128, 0, stream>>>(
      mem, tokw, bidx, ridx, ovf_cnt, ovf, (float*)d_out);
}

// Round 3
// 299.474 us; speedup vs baseline: 1.0723x; 1.0439x over previous
//
#include <hip/hip_runtime.h>

// DiffTreeInterpreter: per-OUTPUT-row CSR gather.
// Build expands each token n (batch b, role rr) into its output contributions
// with op_dist pre-folded:
//   rr even          -> row rr>>1     scale op0*w0   (car)
//   rr odd,  rr>=3   -> row (rr-1)>>1 scale op1*w1   (cdr)
//   rr < 2048        -> row 2*rr      scale op2*w2   (cons1)
//                       row 2*rr+1    scale op2*w3   (cons2)
// plus out[b,1,:] += op2*root_filler[b].
// Gather: one wave per output row, reads exactly its entry list.
// pad-masking in the reference is a numeric no-op (padded rows are all-zero).

namespace {
constexpr int kB = 32;
constexpr int kL = 128;
constexpr int kF = 128;
constexpr int kR = 4096;
constexpr int kN = 262144;
constexpr int kNB = kB * kR;       // 131072 output rows
constexpr int kCapMax = 32;        // max entries per row (lambda<=6 -> P(>32)~1e-15)
constexpr int kOvfMax = 65536;

// workspace layout (bytes)
constexpr size_t kOffCounts  = 0;          // kNB*4 = 524288
constexpr size_t kOffOvfCnt  = 524288;     // 4
constexpr size_t kOffOvf     = 524304;     // kOvfMax*16 = 1048576 (int4, 16B aligned)
constexpr size_t kOffEntries = 1572880;    // kNB*cap*8 (int2), 8B aligned
}  // namespace

__global__ __launch_bounds__(256) void build_kernel(
    const float4* __restrict__ aw, const float* __restrict__ opd,
    const int* __restrict__ bidx, const int* __restrict__ sidx,
    const int* __restrict__ ridx, int cap,
    int* __restrict__ counts, int* __restrict__ ovf_cnt,
    int4* __restrict__ ovf, int2* __restrict__ entries) {
  int n = blockIdx.x * 256 + threadIdx.x;
  if (n >= kN) return;
  int b = bidx[n];
  int s = sidx[n];
  int rr = ridx[n];
  float4 w = aw[b * kL + s];
  float op0 = opd[3 * b + 0];
  float op1 = opd[3 * b + 1];
  float op2 = opd[3 * b + 2];
  const int base = b << 12;

  auto push = [&](int row, float sc) {
    int key = base | row;
    int pos = atomicAdd(&counts[key], 1);
    if (pos < cap) {
      entries[(size_t)key * cap + pos] = make_int2(n, __float_as_int(sc));
    } else {
      int o = atomicAdd(ovf_cnt, 1);
      if (o < kOvfMax) ovf[o] = make_int4(key, n, __float_as_int(sc), 0);
    }
  };

  if ((rr & 1) == 0) {
    push(rr >> 1, op0 * w.x);           // car
  } else if (rr >= 3) {
    push((rr - 1) >> 1, op1 * w.y);     // cdr
  }
  if (rr < kR / 2) {
    push(2 * rr, op2 * w.z);            // cons1
    push(2 * rr + 1, op2 * w.w);        // cons2
  }
}

// Process predicated chunk of up to 4 entries [i0, i0+4). i0 < cnt guaranteed.
__device__ __forceinline__ void proc4(int i0, int cnt, int2 e,
                                      const float2* __restrict__ mem2, int t,
                                      float& ax, float& ay) {
  // broadcast entry (idx, scale) from lanes i0..i0+3; move to SGPRs
  int n0 = __builtin_amdgcn_readfirstlane(__shfl(e.x, i0 + 0));
  int s0 = __builtin_amdgcn_readfirstlane(__shfl(e.y, i0 + 0));
  int n1 = __builtin_amdgcn_readfirstlane(__shfl(e.x, i0 + 1));
  int s1 = __builtin_amdgcn_readfirstlane(__shfl(e.y, i0 + 1));
  int n2 = __builtin_amdgcn_readfirstlane(__shfl(e.x, i0 + 2));
  int s2 = __builtin_amdgcn_readfirstlane(__shfl(e.y, i0 + 2));
  int n3 = __builtin_amdgcn_readfirstlane(__shfl(e.x, i0 + 3));
  int s3 = __builtin_amdgcn_readfirstlane(__shfl(e.y, i0 + 3));
  const bool v1 = (i0 + 1) < cnt, v2 = (i0 + 2) < cnt, v3 = (i0 + 3) < cnt;
  n1 = v1 ? n1 : 0;  // invalid slots: clamp row idx, zero scale
  n2 = v2 ? n2 : 0;
  n3 = v3 ? n3 : 0;
  float f0 = __int_as_float(s0);
  float f1 = v1 ? __int_as_float(s1) : 0.f;
  float f2 = v2 ? __int_as_float(s2) : 0.f;
  float f3 = v3 ? __int_as_float(s3) : 0.f;
  // independent row loads, one latency round
  float2 m0 = mem2[(size_t)n0 * (kF / 2) + t];
  float2 m1 = mem2[(size_t)n1 * (kF / 2) + t];
  float2 m2 = mem2[(size_t)n2 * (kF / 2) + t];
  float2 m3 = mem2[(size_t)n3 * (kF / 2) + t];
  ax += f0 * m0.x; ay += f0 * m0.y;
  ax += f1 * m1.x; ay += f1 * m1.y;
  ax += f2 * m2.x; ay += f2 * m2.y;
  ax += f3 * m3.x; ay += f3 * m3.y;
}

__global__ __launch_bounds__(256) void gather_kernel(
    const float2* __restrict__ mem2, const float2* __restrict__ root2,
    const float* __restrict__ opd, const int* __restrict__ counts,
    const int2* __restrict__ entries, int cap, float2* __restrict__ out2) {
  const int row = blockIdx.x * 4 + (threadIdx.x >> 6);  // one wave per output row
  const int t = threadIdx.x & 63;                       // lane: features 2t, 2t+1
  int cnt = min(counts[row], cap);
  cnt = __builtin_amdgcn_readfirstlane(cnt);

  float ax = 0.f, ay = 0.f;
  if (cnt > 0) {
    // only valid slots issue loads (exec-masked) -> minimal entry traffic
    int2 e = make_int2(0, 0);
    if (t < cnt) e = entries[(size_t)row * cap + t];
    for (int i = 0; i < cnt; i += 4) proc4(i, cnt, e, mem2, t, ax, ay);
  }

  const int r = row & (kR - 1);
  if (r == 1) {
    const int b = row >> 12;
    float op2 = opd[3 * b + 2];
    float2 rf = root2[b * (kF / 2) + t];
    ax += op2 * rf.x;
    ay += op2 * rf.y;
  }
  float2 o;
  o.x = ax;
  o.y = ay;
  out2[(size_t)row * (kF / 2) + t] = o;
}

// Overflow fallback (expected ~0 entries): direct atomic add.
// Must run AFTER gather_kernel (gather writes out with '=').
__global__ __launch_bounds__(128) void ovf_kernel(
    const float* __restrict__ mem, const int* __restrict__ ovf_cnt,
    const int4* __restrict__ ovf, float* __restrict__ out) {
  int m = *ovf_cnt;
  if (m > kOvfMax) m = kOvfMax;
  const int t = threadIdx.x;  // feature 0..127
  for (int i = blockIdx.x; i < m; i += gridDim.x) {
    int4 e = ovf[i];
    float sc = __int_as_float(e.z);
    atomicAdd(&out[(size_t)e.x * kF + t], sc * mem[(size_t)e.y * kF + t]);
  }
}

extern "C" void kernel_launch(void* const* d_in, const int* in_sizes, int n_in,
                              void* d_out, int out_size, void* d_ws, size_t ws_size,
                              hipStream_t stream) {
  const float* mem   = (const float*)d_in[0];   // (N, F)
  const float* aw    = (const float*)d_in[1];   // (B, L, 4)
  const float* rootf = (const float*)d_in[2];   // (B, F)
  const float* opd   = (const float*)d_in[3];   // (B, 3)
  const int* bidx    = (const int*)d_in[4];     // (N,)
  const int* sidx    = (const int*)d_in[5];     // (N,)
  const int* ridx    = (const int*)d_in[6];     // (N,)

  char* ws = (char*)d_ws;
  int* counts    = (int*)(ws + kOffCounts);
  int* ovf_cnt   = (int*)(ws + kOffOvfCnt);
  int4* ovf      = (int4*)(ws + kOffOvf);
  int2* entries  = (int2*)(ws + kOffEntries);

  // runtime capacity: fill whatever workspace we have, up to kCapMax
  int cap = kCapMax;
  if (ws_size > kOffEntries) {
    size_t avail = (ws_size - kOffEntries) / ((size_t)kNB * sizeof(int2));
    if (avail < (size_t)cap) cap = (int)avail;
  } else {
    cap = 0;  // everything via overflow path (degenerate, but correct-ish)
  }

  // zero counts + overflow counter (ws is poisoned 0xAA before every call)
  hipMemsetAsync(ws, 0, kOffOvfCnt + 4, stream);

  build_kernel<<<kN / 256, 256, 0, stream>>>(
      (const float4*)aw, opd, bidx, sidx, ridx, cap, counts, ovf_cnt, ovf,
      entries);

  gather_kernel<<<kNB / 4, 256, 0, stream>>>(
      (const float2*)mem, (const float2*)rootf, opd, counts, entries, cap,
      (float2*)d_out);

  ovf_kernel<<<64, 128, 0, stream>>>(mem, ovf_cnt, ovf, (float*)d_out);
}

// Round 4
// 265.272 us; speedup vs baseline: 1.2106x; 1.1289x over previous
//
#include <hip/hip_runtime.h>

// DiffTreeInterpreter: row-pair CSR gather, 2-latency-round edition.
//
// Output row r (batch b):
//   half: r<2048: car from role 2r (scale op0*w0), cdr from role 2r+1>=3 (op1*w1)
//   cons: all r: from role r>>1 (scale op2*w2 if r even else op2*w3)
//   root: out[b,1,:] += op2*root_filler[b]
// One wave handles the row PAIR (2q, 2q+1): cons tokens (role q) are shared ->
// one mem-row load feeds both rows. pad-masking in the reference is a numeric
// no-op (padded rows are all-zero).

namespace {
constexpr int kB = 32;
constexpr int kL = 128;
constexpr int kF = 128;
constexpr int kR = 4096;
constexpr int kN = 262144;
constexpr int kQ = 2048;       // row-pairs per batch == half-rows per batch
constexpr int kNP = kB * kQ;   // 65536 keys
constexpr int kCap = 16;       // entries per record; P(Poisson(4)>16)~4e-7
constexpr int kOvfMax = 65536;

// workspace layout (bytes)
constexpr size_t kOffRowCnt  = 0;        // kNP*4  = 262144
constexpr size_t kOffConsCnt = 262144;   // kNP*4  = 262144
constexpr size_t kOffOvfCnt  = 524288;   // 4 (pad 16)
constexpr size_t kOffOvf     = 524304;   // kOvfMax*16 = 1048576
constexpr size_t kOffRowEnt  = 1572880;  // kNP*kCap*8  = 8388608  (int2)
constexpr size_t kOffConsEnt = 9961488;  // kNP*kCap*16 = 16777216 (int4)
// end: 26,738,704 bytes (~25.5 MB)
}  // namespace

__global__ __launch_bounds__(256) void build_kernel(
    const float4* __restrict__ aw, const float* __restrict__ opd,
    const int* __restrict__ bidx, const int* __restrict__ sidx,
    const int* __restrict__ ridx,
    int* __restrict__ rowcnt, int* __restrict__ conscnt,
    int* __restrict__ ovf_cnt, int4* __restrict__ ovf,
    int2* __restrict__ rowent, int4* __restrict__ consent) {
  int n = blockIdx.x * 256 + threadIdx.x;
  if (n >= kN) return;
  int b = bidx[n];
  int s = sidx[n];
  int rr = ridx[n];
  float4 w = aw[b * kL + s];
  float op0 = opd[3 * b + 0];
  float op1 = opd[3 * b + 1];
  float op2 = opd[3 * b + 2];

  // half contribution -> row rr>>1 (car if even, cdr if odd>=3; role 1 dropped)
  bool even = (rr & 1) == 0;
  if (even || rr >= 3) {
    float sc = even ? op0 * w.x : op1 * w.y;
    int key = (b << 11) | (rr >> 1);
    int pos = atomicAdd(&rowcnt[key], 1);
    if (pos < kCap) {
      rowent[key * kCap + pos] = make_int2(n, __float_as_int(sc));
    } else {
      int o = atomicAdd(ovf_cnt, 1);
      if (o < kOvfMax)
        ovf[o] = make_int4(b * kR + (rr >> 1), n, __float_as_int(sc), 0);
    }
  }
  // cons contribution -> rows 2rr, 2rr+1 : ONE entry (n, s1, s2)
  if (rr < kQ) {
    int key = (b << 11) | rr;
    int pos = atomicAdd(&conscnt[key], 1);
    if (pos < kCap) {
      consent[key * kCap + pos] =
          make_int4(n, __float_as_int(op2 * w.z), __float_as_int(op2 * w.w), 0);
    } else {
      int o = atomicAdd(ovf_cnt, 2);
      if (o < kOvfMax)
        ovf[o] = make_int4(b * kR + 2 * rr, n, __float_as_int(op2 * w.z), 0);
      if (o + 1 < kOvfMax)
        ovf[o + 1] =
            make_int4(b * kR + 2 * rr + 1, n, __float_as_int(op2 * w.w), 0);
    }
  }
}

__global__ __launch_bounds__(256) void gather_kernel(
    const float2* __restrict__ mem2, const float2* __restrict__ root2,
    const float* __restrict__ opd,
    const int* __restrict__ rowcnt, const int* __restrict__ conscnt,
    const int2* __restrict__ rowent, const int2* __restrict__ consent2,
    float2* __restrict__ out2) {
  const int p = blockIdx.x * 4 + (threadIdx.x >> 6);  // pair id = (b<<11)|q
  const int t = threadIdx.x & 63;                     // lane: features 2t,2t+1
  const int b = p >> 11;
  const int q = p & (kQ - 1);
  const bool hashalf = q < 1024;  // rows 2q,2q+1 < 2048

  // ---- round 1: ALL structure loads, fully independent ----
  int cn_raw = conscnt[p];
  int2 ce = make_int2(0, 0);
  if (t < 32) ce = (consent2 + (size_t)p * 2 * kCap)[t];  // 16 int4 = 32 int2
  int2 hc = make_int2(0, 0);
  int2 he = make_int2(0, 0);
  if (hashalf) {
    int key0 = (b << 11) | (q << 1);            // even -> 8B aligned
    hc = *(const int2*)(rowcnt + key0);         // counts for rows 2q, 2q+1
    if (t < 32) he = (rowent + (size_t)key0 * kCap)[t];  // both records, 256B
  }
  int cn = min(__builtin_amdgcn_readfirstlane(cn_raw), kCap);
  int h0 = 0, h1 = 0;
  if (hashalf) {
    h0 = min(__builtin_amdgcn_readfirstlane(hc.x), kCap);
    h1 = min(__builtin_amdgcn_readfirstlane(hc.y), kCap);
  }

  // ---- round 2: issue phase (all mem-row loads independent) ----
  // cons: width 4 (P(Poisson(2)>4)=5% -> tail loop)
  float2 mc[4];
  float c1s[4], c2s[4];
#pragma unroll
  for (int j = 0; j < 4; ++j) {
    c1s[j] = 0.f;
    c2s[j] = 0.f;
    mc[j] = make_float2(0.f, 0.f);
  }
  if (cn > 0) {
#pragma unroll
    for (int j = 0; j < 4; ++j) {
      bool v = j < cn;
      int nn = __shfl(ce.x, 2 * j);
      float a = __int_as_float(__shfl(ce.y, 2 * j));
      float bb = __int_as_float(__shfl(ce.x, 2 * j + 1));
      nn = v ? nn : 0;  // slots >= cn hold 0xAA poison
      c1s[j] = v ? a : 0.f;
      c2s[j] = v ? bb : 0.f;
      mc[j] = mem2[(size_t)nn * (kF / 2) + t];
    }
  }
  // halves: width 8 (P(Poisson(4)>8)=2% -> tail loop)
  float2 m0[8], m1[8];
  float s0a[8], s1a[8];
#pragma unroll
  for (int j = 0; j < 8; ++j) {
    s0a[j] = 0.f;
    s1a[j] = 0.f;
    m0[j] = make_float2(0.f, 0.f);
    m1[j] = make_float2(0.f, 0.f);
  }
  if (h0 > 0) {
#pragma unroll
    for (int j = 0; j < 4; ++j) {
      bool v = j < h0;
      int nn = __shfl(he.x, j);
      float s = __int_as_float(__shfl(he.y, j));
      nn = v ? nn : 0;
      s0a[j] = v ? s : 0.f;
      m0[j] = mem2[(size_t)nn * (kF / 2) + t];
    }
    if (h0 > 4) {
#pragma unroll
      for (int j = 4; j < 8; ++j) {
        bool v = j < h0;
        int nn = __shfl(he.x, j);
        float s = __int_as_float(__shfl(he.y, j));
        nn = v ? nn : 0;
        s0a[j] = v ? s : 0.f;
        m0[j] = mem2[(size_t)nn * (kF / 2) + t];
      }
    }
  }
  if (h1 > 0) {
#pragma unroll
    for (int j = 0; j < 4; ++j) {
      bool v = j < h1;
      int nn = __shfl(he.x, 16 + j);
      float s = __int_as_float(__shfl(he.y, 16 + j));
      nn = v ? nn : 0;
      s1a[j] = v ? s : 0.f;
      m1[j] = mem2[(size_t)nn * (kF / 2) + t];
    }
    if (h1 > 4) {
#pragma unroll
      for (int j = 4; j < 8; ++j) {
        bool v = j < h1;
        int nn = __shfl(he.x, 16 + j);
        float s = __int_as_float(__shfl(he.y, 16 + j));
        nn = v ? nn : 0;
        s1a[j] = v ? s : 0.f;
        m1[j] = mem2[(size_t)nn * (kF / 2) + t];
      }
    }
  }

  // ---- accumulate ----
  float ax0 = 0.f, ay0 = 0.f, ax1 = 0.f, ay1 = 0.f;
#pragma unroll
  for (int j = 0; j < 4; ++j) {
    ax0 += c1s[j] * mc[j].x;
    ay0 += c1s[j] * mc[j].y;
    ax1 += c2s[j] * mc[j].x;
    ay1 += c2s[j] * mc[j].y;
  }
#pragma unroll
  for (int j = 0; j < 8; ++j) {
    ax0 += s0a[j] * m0[j].x;
    ay0 += s0a[j] * m0[j].y;
  }
#pragma unroll
  for (int j = 0; j < 8; ++j) {
    ax1 += s1a[j] * m1[j].x;
    ay1 += s1a[j] * m1[j].y;
  }

  // ---- rare tails ----
  for (int i = 4; i < cn; i += 4) {
#pragma unroll
    for (int j = 0; j < 4; ++j) {
      int idx = i + j;
      bool v = idx < cn;
      int nn = __shfl(ce.x, 2 * idx);
      float a = __int_as_float(__shfl(ce.y, 2 * idx));
      float bb = __int_as_float(__shfl(ce.x, 2 * idx + 1));
      nn = v ? nn : 0;
      a = v ? a : 0.f;
      bb = v ? bb : 0.f;
      float2 m = mem2[(size_t)nn * (kF / 2) + t];
      ax0 += a * m.x;
      ay0 += a * m.y;
      ax1 += bb * m.x;
      ay1 += bb * m.y;
    }
  }
  for (int i = 8; i < h0; i += 4) {
#pragma unroll
    for (int j = 0; j < 4; ++j) {
      int idx = i + j;
      bool v = idx < h0;
      int nn = __shfl(he.x, idx);
      float s = __int_as_float(__shfl(he.y, idx));
      nn = v ? nn : 0;
      s = v ? s : 0.f;
      float2 m = mem2[(size_t)nn * (kF / 2) + t];
      ax0 += s * m.x;
      ay0 += s * m.y;
    }
  }
  for (int i = 8; i < h1; i += 4) {
#pragma unroll
    for (int j = 0; j < 4; ++j) {
      int idx = i + j;
      bool v = idx < h1;
      int nn = __shfl(he.x, 16 + idx);
      float s = __int_as_float(__shfl(he.y, 16 + idx));
      nn = v ? nn : 0;
      s = v ? s : 0.f;
      float2 m = mem2[(size_t)nn * (kF / 2) + t];
      ax1 += s * m.x;
      ay1 += s * m.y;
    }
  }

  // ---- root filler (row 1 <=> q==0) + writeback ----
  if (q == 0) {
    float op2 = opd[3 * b + 2];
    float2 rf = root2[b * (kF / 2) + t];
    ax1 += op2 * rf.x;
    ay1 += op2 * rf.y;
  }
  size_t orow = ((size_t)b * kR + 2 * q) * (kF / 2) + t;
  out2[orow] = make_float2(ax0, ay0);
  out2[orow + (kF / 2)] = make_float2(ax1, ay1);
}

// Overflow fallback (expected ~0 entries): direct atomic add.
// Must run AFTER gather_kernel (gather writes out with '=').
__global__ __launch_bounds__(128) void ovf_kernel(
    const float* __restrict__ mem, const int* __restrict__ ovf_cnt,
    const int4* __restrict__ ovf, float* __restrict__ out) {
  int m = *ovf_cnt;
  if (m > kOvfMax) m = kOvfMax;
  const int t = threadIdx.x;  // feature 0..127
  for (int i = blockIdx.x; i < m; i += gridDim.x) {
    int4 e = ovf[i];
    float sc = __int_as_float(e.z);
    atomicAdd(&out[(size_t)e.x * kF + t], sc * mem[(size_t)e.y * kF + t]);
  }
}

extern "C" void kernel_launch(void* const* d_in, const int* in_sizes, int n_in,
                              void* d_out, int out_size, void* d_ws, size_t ws_size,
                              hipStream_t stream) {
  const float* mem   = (const float*)d_in[0];   // (N, F)
  const float* aw    = (const float*)d_in[1];   // (B, L, 4)
  const float* rootf = (const float*)d_in[2];   // (B, F)
  const float* opd   = (const float*)d_in[3];   // (B, 3)
  const int* bidx    = (const int*)d_in[4];     // (N,)
  const int* sidx    = (const int*)d_in[5];     // (N,)
  const int* ridx    = (const int*)d_in[6];     // (N,)

  char* ws = (char*)d_ws;
  int* rowcnt   = (int*)(ws + kOffRowCnt);
  int* conscnt  = (int*)(ws + kOffConsCnt);
  int* ovf_cnt  = (int*)(ws + kOffOvfCnt);
  int4* ovf     = (int4*)(ws + kOffOvf);
  int2* rowent  = (int2*)(ws + kOffRowEnt);
  int4* consent = (int4*)(ws + kOffConsEnt);

  // zero all counters in one contiguous memset (ws is poisoned 0xAA each call)
  hipMemsetAsync(ws, 0, kOffOvfCnt + 16, stream);

  build_kernel<<<kN / 256, 256, 0, stream>>>(
      (const float4*)aw, opd, bidx, sidx, ridx, rowcnt, conscnt, ovf_cnt, ovf,
      rowent, consent);

  gather_kernel<<<kNP / 4, 256, 0, stream>>>(
      (const float2*)mem, (const float2*)rootf, opd, rowcnt, conscnt, rowent,
      (const int2*)consent, (float2*)d_out);

  ovf_kernel<<<64, 128, 0, stream>>>(mem, ovf_cnt, ovf, (float*)d_out);
}